// Round 4
// baseline (261.667 us; speedup 1.0000x reference)
//
#include <hip/hip_runtime.h>

#define OUT_W 1024
#define OUT_H 1024
#define BOXES 16   // boxes per block; 32768/16 = 2048 blocks

// Native clang vector type (HIP's float4 is a struct; this lowers to
// global_store_dwordx4 directly).
typedef float floatx4 __attribute__((ext_vector_type(4)));

// Single fused pass: each block owns 16 consecutive boxes; 256 threads; per
// box each thread computes one float4 of vector_x and one of vector_y.
//
// Why this shape:
//  - R0 (1 box/block, 32768 blocks) hit only ~2.9 TB/s: each wave did ~150
//    cycles of work against ~1000 cycles of block startup + param-load
//    latency, and 32768 blocks is near the CP dispatch-rate limit.
//  - R2 batched 8 boxes but also switched to nontemporal stores and
//    regressed; the 6.6 TB/s fill kernel uses NORMAL stores, so nt is out.
//  - 16 consecutive boxes -> params are 2x128 B contiguous -> the compiler
//    batches them as s_load_dwordx8/x16 at loop head (full unroll), hiding
//    all scalar-load latency behind the first box's compute.
// Per-lane work per box: 8 v_exp_f32 + ~40 VALU for 32 B stored; VALU
// ceiling ~9 TB/s > HBM write ceiling, so this is store-BW-bound.
__global__ __launch_bounds__(256)
void gv_fused(const float* __restrict__ center,
              const float* __restrict__ wh,
              float* __restrict__ out_x,
              float* __restrict__ out_y,
              int BN)
{
    const int t    = threadIdx.x;
    const int base = blockIdx.x * BOXES;

    const int   p0 = t * 4;
    const float pf0 = (float)p0;

#pragma unroll
    for (int j = 0; j < BOXES; ++j) {
        const int bn = base + j;
        if (bn >= BN) continue;

        const float2 c = reinterpret_cast<const float2*>(center)[bn];
        const float2 w = reinterpret_cast<const float2*>(wh)[bn];
        const float cx = c.x, cy = c.y, Wb = w.x, Hb = w.y;

        // kernel size = floor(W/2)*2 - 1 ; radius = floor((ks-1)/2) ;
        // sigma = floor(r/3) — fp32 exactly like the jnp reference
        const float ksw = floorf(Wb * 0.5f) * 2.0f - 1.0f;
        const float rw  = floorf((ksw - 1.0f) * 0.5f);
        const float sw  = floorf(rw / 3.0f);
        const float ksh = floorf(Hb * 0.5f) * 2.0f - 1.0f;
        const float rh  = floorf((ksh - 1.0f) * 0.5f);
        const float sh  = floorf(rh / 3.0f);

        const bool zero_box = ((cx + cy) + (Wb + Hb)) == 0.0f;

        // SCALE = upscale/stride = 1.0 ; trunc toward zero as astype(int32)
        const float x = truncf(cx);
        const float y = truncf(cy);

        const float ul0 = x - rw;
        const float ul1 = y - rh;
        const float br0 = x + rw + 1.0f;
        const float br1 = y + rh + 1.0f;

        // is_point_in_img: inclusive upper bound
        const bool in_ul = (ul0 >= 0.0f) && (ul0 <= (float)OUT_W) &&
                           (ul1 >= 0.0f) && (ul1 <= (float)OUT_H);
        const bool in_br = (br0 >= 0.0f) && (br0 <= (float)OUT_W) &&
                           (br1 >= 0.0f) && (br1 <= (float)OUT_H);
        const bool active = (!zero_box) && (sw != 0.0f) && (sh != 0.0f) &&
                            (in_ul || in_br);

        // safe sigma (reference guards sig==0 inside exp even though the
        // mask kills it)
        const float ssw = (sw == 0.0f) ? 1.0f : sw;
        const float ssh = (sh == 0.0f) ? 1.0f : sh;
        const float iw  = -1.0f / (2.0f * ssw * ssw);
        const float ih  = -1.0f / (2.0f * ssh * ssh);

        floatx4 vx, vy;
#pragma unroll
        for (int i = 0; i < 4; ++i) {
            const float p  = pf0 + (float)i;
            const float dx = p - x;
            const float dy = p - y;
            const bool mx = active && (p >= ul0) && (p < br0);
            const bool my = active && (p >= ul1) && (p < br1);
            vx[i] = mx ? __expf(dx * dx * iw) : 0.0f;
            vy[i] = my ? __expf(dy * dy * ih) : 0.0f;
        }

        const size_t row = (size_t)bn * (OUT_W / 4) + t;
        reinterpret_cast<floatx4*>(out_x)[row] = vx;
        reinterpret_cast<floatx4*>(out_y)[row] = vy;
    }
}

extern "C" void kernel_launch(void* const* d_in, const int* in_sizes, int n_in,
                              void* d_out, int out_size, void* d_ws, size_t ws_size,
                              hipStream_t stream) {
    const float* center = (const float*)d_in[0];  // [B,N,2]
    const float* wh     = (const float*)d_in[1];  // [B,N,2]
    float* out = (float*)d_out;                   // vector_x ++ vector_y, fp32

    const int BN = in_sizes[0] / 2;               // B*N = 32768
    float* out_x = out;
    float* out_y = out + (size_t)BN * OUT_W;

    const int grid = (BN + BOXES - 1) / BOXES;    // 2048 blocks
    gv_fused<<<dim3(grid), dim3(256), 0, stream>>>(center, wh, out_x, out_y, BN);
}

// Round 5
// 252.476 us; speedup vs baseline: 1.0364x; 1.0364x over previous
//
#include <hip/hip_runtime.h>

#define OUT_W 1024
#define OUT_H 1024
#define BPW   8     // boxes per wave
#define WAVES 4     // waves per block (256 threads)

// Strategy (validated R3): output is ~90% exact zeros. hipMemsetAsync zeroes
// all 268 MB at the runtime fill-path's ~6.5 TB/s (fused compute kernels
// empirically cap at ~3 TB/s on this store pattern — R0/R2/R4); then this
// kernel splats only the nonzero Gaussian windows (~28.6 MB).
//
// R3's splat ran 1 box/wave over 8192 blocks: ~6 store-instructions per wave
// then wave death -> ~0.95 TB/s, latency/launch-bound. Here: 8 boxes/wave,
// 1024 blocks (4/CU, 16 waves/CU). Full unroll lets the compiler hoist all 8
// boxes' scalar param loads to the loop head and keeps ~18 coalesced
// store-iterations in flight per wave.
//
// Window bounds are wave-uniform (derived per box) -> no lane divergence;
// p = xs + lane strides give 64x4 B = 256 B coalesced stores.
__global__ __launch_bounds__(256)
void gv_splat(const float* __restrict__ center,
              const float* __restrict__ wh,
              float* __restrict__ out_x,
              float* __restrict__ out_y,
              int BN)
{
    const int wave = threadIdx.x >> 6;
    const int lane = threadIdx.x & 63;
    const int base = (blockIdx.x * WAVES + wave) * BPW;

#pragma unroll
    for (int j = 0; j < BPW; ++j) {
        const int bn = base + j;
        if (bn >= BN) break;

        const float2 c = reinterpret_cast<const float2*>(center)[bn];
        const float2 w = reinterpret_cast<const float2*>(wh)[bn];
        const float cx = c.x, cy = c.y, Wb = w.x, Hb = w.y;

        // kernel size = floor(W/2)*2 - 1 ; radius = floor((ks-1)/2) ;
        // sigma = floor(r/3) — fp32 exactly like the jnp reference
        const float ksw = floorf(Wb * 0.5f) * 2.0f - 1.0f;
        const float rw  = floorf((ksw - 1.0f) * 0.5f);
        const float sw  = floorf(rw / 3.0f);
        const float ksh = floorf(Hb * 0.5f) * 2.0f - 1.0f;
        const float rh  = floorf((ksh - 1.0f) * 0.5f);
        const float sh  = floorf(rh / 3.0f);

        const bool zero_box = ((cx + cy) + (Wb + Hb)) == 0.0f;

        // SCALE = upscale/stride = 1.0 ; trunc toward zero as astype(int32)
        const float x = truncf(cx);
        const float y = truncf(cy);

        const float ul0 = x - rw;
        const float ul1 = y - rh;
        const float br0 = x + rw + 1.0f;
        const float br1 = y + rh + 1.0f;

        // is_point_in_img: inclusive upper bound
        const bool in_ul = (ul0 >= 0.0f) && (ul0 <= (float)OUT_W) &&
                           (ul1 >= 0.0f) && (ul1 <= (float)OUT_H);
        const bool in_br = (br0 >= 0.0f) && (br0 <= (float)OUT_W) &&
                           (br1 >= 0.0f) && (br1 <= (float)OUT_H);
        const bool active = (!zero_box) && (sw != 0.0f) && (sh != 0.0f) &&
                            (in_ul || in_br);
        if (!active) continue;   // memset already wrote the zeros

        const float iw = -1.0f / (2.0f * sw * sw);   // active => sw,sh != 0
        const float ih = -1.0f / (2.0f * sh * sh);

        // x, rw etc. are integer-valued floats well inside int range
        const int xs = max(0, (int)ul0);
        const int xe = min(OUT_W, (int)br0);
        const int ys = max(0, (int)ul1);
        const int ye = min(OUT_H, (int)br1);

        float* __restrict__ rowx = out_x + (size_t)bn * OUT_W;
        float* __restrict__ rowy = out_y + (size_t)bn * OUT_W;

        for (int p = xs + lane; p < xe; p += 64) {
            const float dx = (float)p - x;
            rowx[p] = __expf(dx * dx * iw);
        }
        for (int p = ys + lane; p < ye; p += 64) {
            const float dy = (float)p - y;
            rowy[p] = __expf(dy * dy * ih);
        }
    }
}

extern "C" void kernel_launch(void* const* d_in, const int* in_sizes, int n_in,
                              void* d_out, int out_size, void* d_ws, size_t ws_size,
                              hipStream_t stream) {
    const float* center = (const float*)d_in[0];  // [B,N,2]
    const float* wh     = (const float*)d_in[1];  // [B,N,2]
    float* out = (float*)d_out;                   // vector_x ++ vector_y, fp32

    const int BN = in_sizes[0] / 2;               // B*N = 32768
    float* out_x = out;
    float* out_y = out + (size_t)BN * OUT_W;

    // Zero all 268 MB via the runtime's fill path (~6.5 TB/s), then splat
    // only the nonzero Gaussian windows (~28.6 MB).
    hipMemsetAsync(d_out, 0, (size_t)out_size, stream);

    const int grid = (BN + WAVES * BPW - 1) / (WAVES * BPW);   // 1024 blocks
    gv_splat<<<dim3(grid), dim3(256), 0, stream>>>(center, wh, out_x, out_y, BN);
}